// Round 7
// baseline (1698.192 us; speedup 1.0000x reference)
//
#include <hip/hip_runtime.h>
#include <hip/hip_bf16.h>

using bf16 = __hip_bfloat16;
typedef __attribute__((ext_vector_type(8))) short bfrag;   // 8 bf16 (4 VGPRs)
typedef __attribute__((ext_vector_type(4))) float ffrag;   // 4 fp32 acc

constexpr int kH  = 32;    // hidden
constexpr int kE  = 64;    // embed
constexpr int kV  = 258;   // vocab
constexpr int kB  = 16;    // batch
constexpr int kR  = 64;    // rows
constexpr int kS  = 64;    // cols
constexpr int kG  = 96;    // 3*H
constexpr int kEP = 65;    // E+1

// ---------------- workspace layout (unchanged) ----------------
constexpr int H2_OFF   = (3*kB*kR*kS*kH)/2;
constexpr int PROG_OFF = H2_OFF;                      // 48 ints: channel pipeline progress
constexpr int T_OFF    = H2_OFF + kB*kR*kH;           // [3][258][96]  emb@Wih0[:, :64].T (+bias fold)
constexpr int WPH_OFF  = T_OFF + 3*kV*kG;             // [3][96][32]   Wih0 @ h2e_W  fold
constexpr int WADP_OFF = WPH_OFF + 3*kG*kH;           // [2][96][32]   Wih0 @ adp_W  fold
constexpr int C0_OFF   = WADP_OFF + 2*kG*kH;          // [3][96]
constexpr int RW_OFF   = C0_OFF + 3*kG;               // [3][96]
constexpr int TG_OFF   = RW_OFF + 3*kG;               // [258][258]
constexpr int TBR_OFF  = TG_OFF + kV*kV;              // [258][258]
constexpr int TBG_OFF  = TBR_OFF + kV*kV;             // [258][258]
constexpr int P_EMB    = TBG_OFF + kV*kV;
constexpr int P_WIH0   = P_EMB    + 3*kV*kE;
constexpr int P_WIHR   = P_WIH0   + 3*kG*kEP;
constexpr int P_WHH    = P_WIHR   + 3*2*kG*kH;
constexpr int P_BIH    = P_WHH    + 3*3*kG*kH;
constexpr int P_BHH    = P_BIH    + 3*3*kG;
constexpr int P_H2EW   = P_BHH    + 3*3*kG;
constexpr int P_H2EB   = P_H2EW   + 3*kEP*kH;
constexpr int P_ADPW   = P_H2EB   + 3*kEP;
constexpr int P_ADPB   = P_ADPW   + 2*kEP*kH;
constexpr int P_REDW   = P_ADPB   + 2*kEP;
constexpr int P_REDB   = P_REDW   + kV*kH;
constexpr int P_GREENW = P_REDB   + kV;
constexpr int P_GREENB = P_GREENW + kV*(kH+kE);
constexpr int P_BLUEW  = P_GREENB + kV;
constexpr int P_BLUEB  = P_BLUEW  + kV*(kH+2*kE);
constexpr int WS_END   = P_BLUEB  + kV;               // ~14.0 MB

__device__ __forceinline__ float tof(bf16 h) { return __bfloat162float(h); }

__device__ __forceinline__ unsigned short bfbits(bf16 h) {
  union { bf16 h; unsigned short u; } cv; cv.h = h; return cv.u;
}
__device__ __forceinline__ short f2b(float v) {
  return (short)bfbits(__float2bfloat16(v));
}
__device__ __forceinline__ float b2f(short s) {
  union { unsigned short u; } cv; cv.u = (unsigned short)s;
  bf16 h; __builtin_memcpy(&h, &cv.u, 2); return __bfloat162float(h);
}
// fast reciprocal (v_rcp_f32, ~1ulp) -- replaces IEEE division (~10 instr each,
// ~720 VALU instr/step in the gate math). bf16 output quantization (4e-3)
// dwarfs the 1e-7 rcp error.
__device__ __forceinline__ float frcp(float x) {
  float r; asm("v_rcp_f32 %0, %1" : "=v"(r) : "v"(x)); return r;
}
__device__ __forceinline__ float sigm(float v) { return frcp(1.0f + __expf(-v)); }
__device__ __forceinline__ float tanh_(float v) { return 1.0f - 2.0f*frcp(__expf(2.0f*v) + 1.0f); }

#define MFMA16(a, bb, cc) __builtin_amdgcn_mfma_f32_16x16x32_bf16((a), (bb), (cc), 0, 0, 0)

// LDS-only barrier: raw s_barrier with lgkmcnt(0) only -- vmem (outs stores,
// T/po/x prefetch loads) stays in flight across it.
__device__ __forceinline__ void lds_barrier() {
  __builtin_amdgcn_sched_barrier(0);
  asm volatile("s_waitcnt lgkmcnt(0)" ::: "memory");
  __builtin_amdgcn_s_barrier();
  __builtin_amdgcn_sched_barrier(0);
}

// ---------------- dtype detect + normalize to fp32 (unchanged, verified) ----------------
__global__ void norm_kernel(const void* p0, const void* p1, const void* p2, const void* p3,
                            const void* p4, const void* p5, const void* p6, const void* p7,
                            const void* p8, const void* p9, const void* p10, const void* p11,
                            const void* p12, const void* p13, const void* p14, const void* p15,
                            float* __restrict__ wsf)
{
  constexpr int counts[16] = {3*kV*kE, 3*kG*kEP, 3*2*kG*kH, 3*3*kG*kH, 3*3*kG, 3*3*kG,
                              3*kEP*kH, 3*kEP, 2*kEP*kH, 2*kEP, kV*kH, kV,
                              kV*(kH+kE), kV, kV*(kH+2*kE), kV};
  constexpr int dsts[16] = {P_EMB, P_WIH0, P_WIHR, P_WHH, P_BIH, P_BHH,
                            P_H2EW, P_H2EB, P_ADPW, P_ADPB, P_REDW, P_REDB,
                            P_GREENW, P_GREENB, P_BLUEW, P_BLUEB};
  const void* srcs[16] = {p0,p1,p2,p3,p4,p5,p6,p7,p8,p9,p10,p11,p12,p13,p14,p15};

  __shared__ unsigned int smax;
  const int a = blockIdx.x;
  const void* src = srcs[a];
  const int n = counts[a];
  if (threadIdx.x == 0) smax = 0;
  if (a == 0) {
    int* prog = (int*)(wsf + PROG_OFF);
    for (int i = threadIdx.x; i < 48; i += 256) prog[i] = 0;
  }
  __syncthreads();

  const unsigned short* u16 = (const unsigned short*)src;
  const int ns = (n < 2048) ? n : 2048;
  unsigned int lm = 0;
  for (int i = threadIdx.x; i < ns; i += 256) {
    unsigned int e = ((unsigned int)u16[i] >> 7) & 0xFFu;
    if (e > lm) lm = e;
  }
  atomicMax(&smax, lm);
  __syncthreads();

  const bool isf32 = (smax >= 135);
  float* dst = wsf + dsts[a];
  if (isf32) {
    const float* s = (const float*)src;
    for (int i = threadIdx.x; i < n; i += 256) dst[i] = s[i];
  } else {
    const bf16* s = (const bf16*)src;
    for (int i = threadIdx.x; i < n; i += 256) dst[i] = tof(s[i]);
  }
}

// ---------------- prep: fold tables & matrices (unchanged, verified) ----------------
__global__ void prep_kernel(float* __restrict__ wsf)
{
  int idx = blockIdx.x * 256 + threadIdx.x;

  if (idx < 3*kV*kG) {
    int c = idx / (kV*kG);
    int rem = idx - c*(kV*kG);
    int v = rem / kG;
    int j = rem - v*kG;
    const float* ev = wsf + P_EMB + (c*kV + v)*kE;
    const float* wr = wsf + P_WIH0 + (c*kG + j)*kEP;
    float acc = 0.f;
    for (int e = 0; e < kE; ++e) acc = fmaf(ev[e], wr[e], acc);
    wsf[T_OFF + idx] = acc;
    return;
  }
  idx -= 3*kV*kG;

  if (idx < 3*kG*kH) {
    int c = idx / (kG*kH);
    int rem = idx - c*(kG*kH);
    int j = rem >> 5;
    int k = rem & 31;
    const float* wr = wsf + P_WIH0 + (c*kG + j)*kEP;
    const float* hw = wsf + P_H2EW + c*kEP*kH + k;
    float acc = 0.f;
    for (int e = 0; e < kEP; ++e) acc = fmaf(wr[e], hw[e*kH], acc);
    wsf[WPH_OFF + idx] = acc;
    return;
  }
  idx -= 3*kG*kH;

  if (idx < 2*kG*kH) {
    int cm = idx / (kG*kH);
    int rem = idx - cm*(kG*kH);
    int j = rem >> 5;
    int k = rem & 31;
    const float* wr = wsf + P_WIH0 + ((cm+1)*kG + j)*kEP;
    const float* aw = wsf + P_ADPW + cm*kEP*kH + k;
    float acc = 0.f;
    for (int e = 0; e < kEP; ++e) acc = fmaf(wr[e], aw[e*kH], acc);
    wsf[WADP_OFF + idx] = acc;
    return;
  }
  idx -= 2*kG*kH;

  if (idx < 3*kG) {
    int c = idx / kG;
    int j = idx - c*kG;
    const float* wr = wsf + P_WIH0 + (c*kG + j)*kEP;
    float acc = wsf[P_BIH + (c*3 + 0)*kG + j];
    for (int e = 0; e < kEP; ++e) acc = fmaf(wsf[P_H2EB + c*kEP + e], wr[e], acc);
    if (c > 0)
      for (int e = 0; e < kEP; ++e) acc = fmaf(wsf[P_ADPB + (c-1)*kEP + e], wr[e], acc);
    wsf[C0_OFF + idx] = acc;
    return;
  }
  idx -= 3*kG;

  if (idx < 3*kG) {
    int c = idx / kG;
    int j = idx - c*kG;
    wsf[RW_OFF + idx] = wsf[P_WIH0 + (c*kG + j)*kEP + kE];
    return;
  }
  idx -= 3*kG;

  if (idx < kV*kV) {
    int v = idx / kV, w = idx - (idx / kV)*kV;
    const float* ev = wsf + P_EMB + v*kE;
    const float* gw = wsf + P_GREENW + w*(kH + kE) + kH;
    float acc = 0.f;
    for (int e = 0; e < kE; ++e) acc = fmaf(ev[e], gw[e], acc);
    wsf[TG_OFF + idx] = acc;
    return;
  }
  idx -= kV*kV;

  if (idx < kV*kV) {
    int v = idx / kV, w = idx - (idx / kV)*kV;
    const float* ev = wsf + P_EMB + v*kE;
    const float* bw = wsf + P_BLUEW + w*(kH + 2*kE) + kH;
    float acc = 0.f;
    for (int e = 0; e < kE; ++e) acc = fmaf(ev[e], bw[e], acc);
    wsf[TBR_OFF + idx] = acc;
    return;
  }
  idx -= kV*kV;

  if (idx < kV*kV) {
    int v = idx / kV, w = idx - (idx / kV)*kV;
    const float* ev = wsf + P_EMB + (kV + v)*kE;
    const float* bw = wsf + P_BLUEW + w*(kH + 2*kE) + kH + kE;
    float acc = 0.f;
    for (int e = 0; e < kE; ++e) acc = fmaf(ev[e], bw[e], acc);
    wsf[TBG_OFF + idx] = acc;
  }
}

// ---------------- fold layer-0 gate constants into T (verified round 4) ----------------
__global__ void tfold_kernel(float* __restrict__ wsf)
{
  int idx = blockIdx.x * 256 + threadIdx.x;
  if (idx >= 3*kV*kG) return;
  int c = idx / (kV*kG);
  int g = idx % kG;
  float add = wsf[C0_OFF + c*kG + g];
  if (g < 2*kH) add += wsf[P_BHH + (c*3 + 0)*kG + g];
  wsf[T_OFF + idx] += add;
}

// ---------------- fused 3-channel MFMA wavefront recurrence ----------------
// Round-6 lesson: step = per-wave serial chain at 1 wave/SIMD -- ~27% VALU issue,
// ~73% exposed latency that same-channel waves cannot fill (barrier-locked).
// This round: TWO BATCHES PER WG (24 WGs x 512 thr = 8 waves = 2 batches x 4):
// 2 independent chunk streams per SIMD -> stream B's issue fills stream A's
// stalls. Per-thread work/registers unchanged (208 < 256 cap at 2 waves/EU).
// Chain cuts: IEEE div -> v_rcp in gates; x-index pipelined 2 diagonals ahead
// (was an in-chain dependent-global before the T gathers); single barrier/step
// (release moved after the barrier; drain-before-barrier still precedes it);
// rpw*rwt folded into the T prefetch.
__global__ __launch_bounds__(512, 2)
void recur_all_kernel(const int* __restrict__ x, float* __restrict__ wsf)
{
  __shared__ __align__(16) short RING[2][2][kR][kH];  // [half][slot][row][hid]
  __shared__ __align__(16) short H0L[2][kR][kH];
  __shared__ __align__(16) short H1L[2][kR][kH];

  const int wg = blockIdx.x;        // 24 WGs: c*8 + p
  const int c  = wg >> 3;
  const int p  = wg & 7;
  const int tid  = threadIdx.x;
  const int half = tid >> 8;        // batch half within WG
  const int b    = p*2 + half;
  const int t2   = tid & 255;
  const int w    = t2 >> 6;         // wave id within half: 16-row band
  const int lane = tid & 63;
  const int m    = lane & 15;
  const int q    = lane >> 4;
  const int ln   = m;
  const int cb0  = w * 16;

  for (int i = tid; i < 2*2*kR*kH; i += 512) (&RING[0][0][0][0])[i] = 0;
  for (int i = tid; i < 2*kR*kH;   i += 512) (&H0L[0][0][0])[i] = 0;
  for (int i = tid; i < 2*kR*kH;   i += 512) (&H1L[0][0][0])[i] = 0;

  // ---- 7 weight matrices as register B-fragments (c-dependent only) ----
  // 0:Wph 1:Whh0 2:Wih1 3:Whh1 4:Wih2 5:Whh2 6:Wadp
  const float* wsrc[7];
  wsrc[0] = wsf + WPH_OFF + c*kG*kH;
  wsrc[1] = wsf + P_WHH  + (c*3+0)*kG*kH;
  wsrc[2] = wsf + P_WIHR + (c*2+0)*kG*kH;
  wsrc[3] = wsf + P_WHH  + (c*3+1)*kG*kH;
  wsrc[4] = wsf + P_WIHR + (c*2+1)*kG*kH;
  wsrc[5] = wsf + P_WHH  + (c*3+2)*kG*kH;
  wsrc[6] = (c > 0) ? (wsf + WADP_OFF + (c-1)*kG*kH) : (wsf + WPH_OFF);
  bfrag Wb[7][6];
#pragma unroll
  for (int mt = 0; mt < 7; ++mt) {
#pragma unroll
    for (int u = 0; u < 6; ++u) {
      const float* pp = wsrc[mt] + (u*16 + ln)*kH + q*8;
#pragma unroll
      for (int j = 0; j < 8; ++j) Wb[mt][u][j] = f2b(pp[j]);
    }
  }

  // ---- per-lane gate constants (layer-0 c0/bias folded into T by tfold) ----
  float rwt[6], bh0n[2], bi1z[4], bi1n[2], bh1n[2], bi2z[4], bi2n[2], bh2n[2];
#pragma unroll
  for (int u = 0; u < 6; ++u) rwt[u] = wsf[RW_OFF + c*kG + u*16 + ln];
#pragma unroll
  for (int u = 0; u < 4; ++u) {
    int g = u*16 + ln;
    bi1z[u] = wsf[P_BIH + (c*3+1)*kG + g] + wsf[P_BHH + (c*3+1)*kG + g];
    bi2z[u] = wsf[P_BIH + (c*3+2)*kG + g] + wsf[P_BHH + (c*3+2)*kG + g];
  }
#pragma unroll
  for (int s2 = 0; s2 < 2; ++s2) {
    int g = 64 + s2*16 + ln;
    bh0n[s2] = wsf[P_BHH + (c*3+0)*kG + g];
    bi1n[s2] = wsf[P_BIH + (c*3+1)*kG + g];
    bh1n[s2] = wsf[P_BHH + (c*3+1)*kG + g];
    bi2n[s2] = wsf[P_BIH + (c*3+2)*kG + g];
    bh2n[s2] = wsf[P_BHH + (c*3+2)*kG + g];
  }

  float h0s[8], h1s[8], h2s[8];
#pragma unroll
  for (int i = 0; i < 8; ++i) { h0s[i] = 0.f; h1s[i] = 0.f; h2s[i] = 0.f; }

  unsigned short* outsAll = (unsigned short*)wsf;
  unsigned short* outsC = outsAll + (size_t)(c*kB + b) * (kR*kS*kH);
  const unsigned short* outsP = outsAll + (size_t)(((c > 0 ? c : 1) - 1)*kB + b) * (kR*kS*kH);
  int* prog = (int*)(wsf + PROG_OFF);
  const int* xc = x + (b*3 + c) * kR * kS;
  const float* Tc = wsf + T_OFF + (size_t)c * kV * kG;

  int rr0[4]; float rpw[4];
#pragma unroll
  for (int i = 0; i < 4; ++i) {
    rr0[i] = cb0 + q*4 + i;
    rpw[i] = (float)rr0[i] * (2.0f/64.0f) - 1.0f;
  }

  // ---- prefetch pipeline state ----
  // tv  = T(d) + rpw*rwt  (ready for current diagonal)
  // xin = x(d+1)           (x loaded 2 diagonals ahead of its T consume)
  // poPre = producer outs fragment for diagonal d
  float tv[6][4];
  int   xin[4];
  bfrag poPre;
  const int d0 = -c*4;   // DELTA=4
  {
#pragma unroll
    for (int i = 0; i < 4; ++i) {
      int sv = d0 - rr0[i];
      int scl = sv < 0 ? 0 : (sv > 63 ? 63 : sv);
      xin[i] = xc[rr0[i]*kS + scl];
    }
#pragma unroll
    for (int i = 0; i < 4; ++i) {
      const float* tp = Tc + (size_t)xin[i]*kG;
#pragma unroll
      for (int u = 0; u < 6; ++u) tv[u][i] = tp[u*16 + ln] + rpw[i]*rwt[u];
    }
#pragma unroll
    for (int i = 0; i < 4; ++i) {
      int sv = d0 + 1 - rr0[i];
      int scl = sv < 0 ? 0 : (sv > 63 ? 63 : sv);
      xin[i] = xc[rr0[i]*kS + scl];
    }
#pragma unroll
    for (int j = 0; j < 8; ++j) poPre[j] = 0;
  }

  // advance pipeline for diagonal d: tv <- T(d+1) from xin, xin <- x(d+2),
  // poPre <- outsP(d+1). All addresses clamped; garbage results never consumed.
  auto do_prefetch = [&](int d) {
#pragma unroll
    for (int i = 0; i < 4; ++i) {
      const float* tp = Tc + (size_t)xin[i]*kG;
#pragma unroll
      for (int u = 0; u < 6; ++u) tv[u][i] = tp[u*16 + ln] + rpw[i]*rwt[u];
    }
#pragma unroll
    for (int i = 0; i < 4; ++i) {
      int sv = d + 2 - rr0[i];
      int scl = sv < 0 ? 0 : (sv > 63 ? 63 : sv);
      xin[i] = xc[rr0[i]*kS + scl];
    }
    {
      int sv = d + 1 - (cb0 + m);
      int scl = sv < 0 ? 0 : (sv > 63 ? 63 : sv);
      poPre = *(const bfrag*)&outsP[((size_t)(cb0 + m)*kS + scl)*kH + q*8];
    }
  };

  __syncthreads();

  constexpr int DELTA = 4;
  constexpr int TT = (kR + kS - 1) + 2*DELTA;   // 135
  for (int t = 0; t < TT; ++t) {
    const int d = t - c*DELTA;

    // consumer poll (one lane per half) BEFORE the barrier
    if (t2 == 0 && c > 0 && d >= -1 && d <= 125) {
      const int need = d + 2;
      while (__hip_atomic_load(&prog[(c-1)*16 + b], __ATOMIC_ACQUIRE,
                               __HIP_MEMORY_SCOPE_AGENT) < need) { }
    }
    lds_barrier();   // the single per-step barrier: ring(d-1) visible, poll done
    // producer release AFTER the barrier: all threads' step-(d-1) stores were
    // vmcnt(0)-drained before they entered this barrier.
    if (t2 == 0 && c < 2 && d >= 1 && d <= 127)
      __hip_atomic_store(&prog[c*16 + b], d, __ATOMIC_RELEASE, __HIP_MEMORY_SCOPE_AGENT);

    const bool activ = (d >= cb0) && (d <= cb0 + 78);
    if (activ) {
      const int ps = (d - 1) & 1;
      const int cs = d & 1;

      int ssv[4];
      bool act[4];
#pragma unroll
      for (int i = 0; i < 4; ++i) {
        ssv[i] = d - rr0[i];
        act[i] = ((unsigned)ssv[i]) < 64u;
      }
      const int row = cb0 + m;

      bfrag phA, h0A;
      {
        int pr = row - 1;
        int prc = pr < 0 ? 0 : pr;
        phA = *(const bfrag*)&RING[half][ps][prc][q*8];
        if (pr < 0) {
#pragma unroll
          for (int j = 0; j < 8; ++j) phA[j] = 0;
        }
        h0A = *(const bfrag*)&H0L[half][row][q*8];
      }
      bfrag poA = poPre;   // prefetched last iteration

      // ---- layer 0: zero-init, MFMA chain, T-add after ----
      ffrag rz[4], gn[2], hn[2];
#pragma unroll
      for (int u = 0; u < 4; ++u)
#pragma unroll
        for (int i = 0; i < 4; ++i) rz[u][i] = 0.f;
#pragma unroll
      for (int s2 = 0; s2 < 2; ++s2)
#pragma unroll
        for (int i = 0; i < 4; ++i) { gn[s2][i] = 0.f; hn[s2][i] = bh0n[s2]; }

#pragma unroll
      for (int u = 0; u < 4; ++u)
        rz[u] = MFMA16(phA, Wb[0][u], rz[u]);
#pragma unroll
      for (int s2 = 0; s2 < 2; ++s2)
        gn[s2] = MFMA16(phA, Wb[0][4+s2], gn[s2]);
      if (c > 0) {
#pragma unroll
        for (int u = 0; u < 4; ++u)
          rz[u] = MFMA16(poA, Wb[6][u], rz[u]);
#pragma unroll
        for (int s2 = 0; s2 < 2; ++s2)
          gn[s2] = MFMA16(poA, Wb[6][4+s2], gn[s2]);
      }
#pragma unroll
      for (int u = 0; u < 4; ++u)
        rz[u] = MFMA16(h0A, Wb[1][u], rz[u]);
#pragma unroll
      for (int s2 = 0; s2 < 2; ++s2)
        hn[s2] = MFMA16(h0A, Wb[1][4+s2], hn[s2]);

      // consume prefetched T (rpw*rwt already folded in)
#pragma unroll
      for (int u = 0; u < 4; ++u)
#pragma unroll
        for (int i = 0; i < 4; ++i) rz[u][i] += tv[u][i];
#pragma unroll
      for (int s2 = 0; s2 < 2; ++s2)
#pragma unroll
        for (int i = 0; i < 4; ++i) gn[s2][i] += tv[4+s2][i];

      // advance pipeline now: loads age across gates + layers 1-2 before the
      // end-of-step vmcnt(0) drain (c<2) sees them.
      do_prefetch(d);

#pragma unroll
      for (int i = 0; i < 4; ++i)
#pragma unroll
        for (int th = 0; th < 2; ++th) {
          float rg = sigm(rz[th][i]);
          float zg = sigm(rz[2+th][i]);
          float ng = tanh_(gn[th][i] + rg*hn[th][i]);
          float h0v = (1.f - zg)*ng + zg*h0s[i*2+th];
          if (act[i]) {
            h0s[i*2+th] = h0v;
            H0L[half][rr0[i]][th*16 + ln] = f2b(h0v);
          }
        }
      bfrag h0An = *(const bfrag*)&H0L[half][row][q*8];

      // ---- layer 1 ----
      bfrag h1A = *(const bfrag*)&H1L[half][row][q*8];
      ffrag rz1[4], gn1[2], hn1[2];
#pragma unroll
      for (int u = 0; u < 4; ++u)
#pragma unroll
        for (int i = 0; i < 4; ++i) rz1[u][i] = bi1z[u];
#pragma unroll
      for (int s2 = 0; s2 < 2; ++s2)
#pragma unroll
        for (int i = 0; i < 4; ++i) { gn1[s2][i] = bi1n[s2]; hn1[s2][i] = bh1n[s2]; }
#pragma unroll
      for (int u = 0; u < 4; ++u) {
        rz1[u] = MFMA16(h0An, Wb[2][u], rz1[u]);
        rz1[u] = MFMA16(h1A,  Wb[3][u], rz1[u]);
      }
#pragma unroll
      for (int s2 = 0; s2 < 2; ++s2) {
        gn1[s2] = MFMA16(h0An, Wb[2][4+s2], gn1[s2]);
        hn1[s2] = MFMA16(h1A,  Wb[3][4+s2], hn1[s2]);
      }
#pragma unroll
      for (int i = 0; i < 4; ++i)
#pragma unroll
        for (int th = 0; th < 2; ++th) {
          float rg = sigm(rz1[th][i]);
          float zg = sigm(rz1[2+th][i]);
          float ng = tanh_(gn1[th][i] + rg*hn1[th][i]);
          float h1v = (1.f - zg)*ng + zg*h1s[i*2+th];
          if (act[i]) {
            h1s[i*2+th] = h1v;
            H1L[half][rr0[i]][th*16 + ln] = f2b(h1v);
          }
        }
      bfrag h1An = *(const bfrag*)&H1L[half][row][q*8];

      // ---- layer 2 ----
      bfrag h2A = *(const bfrag*)&RING[half][ps][row][q*8];
      if (m == d - cb0) {            // s==0 row: no left neighbor
#pragma unroll
        for (int j = 0; j < 8; ++j) h2A[j] = 0;
      }
      ffrag rz2[4], gn2[2], hn2[2];
#pragma unroll
      for (int u = 0; u < 4; ++u)
#pragma unroll
        for (int i = 0; i < 4; ++i) rz2[u][i] = bi2z[u];
#pragma unroll
      for (int s2 = 0; s2 < 2; ++s2)
#pragma unroll
        for (int i = 0; i < 4; ++i) { gn2[s2][i] = bi2n[s2]; hn2[s2][i] = bh2n[s2]; }
#pragma unroll
      for (int u = 0; u < 4; ++u) {
        rz2[u] = MFMA16(h1An, Wb[4][u], rz2[u]);
        rz2[u] = MFMA16(h2A,  Wb[5][u], rz2[u]);
      }
#pragma unroll
      for (int s2 = 0; s2 < 2; ++s2) {
        gn2[s2] = MFMA16(h1An, Wb[4][4+s2], gn2[s2]);
        hn2[s2] = MFMA16(h2A,  Wb[5][4+s2], hn2[s2]);
      }
#pragma unroll
      for (int i = 0; i < 4; ++i)
#pragma unroll
        for (int th = 0; th < 2; ++th) {
          float rg = sigm(rz2[th][i]);
          float zg = sigm(rz2[2+th][i]);
          float ng = tanh_(gn2[th][i] + rg*hn2[th][i]);
          float h2old = (ssv[i] == 0) ? 0.f : h2s[i*2+th];
          float h2v = (1.f - zg)*ng + zg*h2old;
          if (act[i]) {
            h2s[i*2+th] = h2v;
            short hb = f2b(h2v);
            RING[half][cs][rr0[i]][th*16 + ln] = hb;
            outsC[((size_t)rr0[i]*kS + ssv[i])*kH + th*16 + ln] = (unsigned short)hb;
          }
        }
    } else {
      do_prefetch(d);   // keep the pipeline advancing through prologue/epilogue
    }

    // producers: drain own vmem so next step's release (after the barrier)
    // covers all threads' outs stores. Prefetch loads were issued early and
    // have aged through the gate/L1/L2 phases.
    if (c < 2) {
      __builtin_amdgcn_sched_barrier(0);
      asm volatile("s_waitcnt vmcnt(0)" ::: "memory");
    }
  }
}

// ---------------- logits epilogue: MFMA GEMM (verified round 6) ----------------
__global__ __launch_bounds__(256, 1)
void logits_kernel(const int* __restrict__ target, const float* __restrict__ wsf,
                   float* __restrict__ out)
{
  const int bx = blockIdx.x;
  const int ch = bx >> 10;          // 1024 WGs per channel
  const int b  = (bx >> 6) & 15;
  const int r  = bx & 63;

  const int tid  = threadIdx.x;
  const int wave = tid >> 6;
  const int lane = tid & 63;
  const int ln   = lane & 15;
  const int q    = lane >> 4;

  const int s0  = wave * 16;
  const int rsb = r * 64 + s0;      // first position of this wave's 16-pos strip

  const unsigned short* outsAll = (const unsigned short*)wsf;
  const unsigned short* hvp = outsAll + (size_t)(ch*kB + b)*(kR*kS*kH)
                                      + (size_t)(rsb + ln)*kH + q*8;
  bfrag hvA = *(const bfrag*)hvp;

  int trv[4], tgv[4];
  if (ch >= 1) {
    const int* tgt0 = target + (b*3 + 0)*4096;
#pragma unroll
    for (int i = 0; i < 4; ++i) trv[i] = tgt0[rsb + q*4 + i];
  }
  if (ch == 2) {
    const int* tgt1 = target + (b*3 + 1)*4096;
#pragma unroll
    for (int i = 0; i < 4; ++i) tgv[i] = tgt1[rsb + q*4 + i];
  }

  const float* wbase; const float* bbase; int wstride;
  if (ch == 0)      { wbase = wsf + P_REDW;   bbase = wsf + P_REDB;   wstride = kH; }
  else if (ch == 1) { wbase = wsf + P_GREENW; bbase = wsf + P_GREENB; wstride = kH + kE; }
  else              { wbase = wsf + P_BLUEW;  bbase = wsf + P_BLUEB;  wstride = kH + 2*kE; }

  const size_t obase = ((size_t)(b*3 + ch)*4096 + rsb);
  const float* TGt  = wsf + TG_OFF;
  const float* TBRt = wsf + TBR_OFF;
  const float* TBGt = wsf + TBG_OFF;

#pragma unroll
  for (int t = 0; t < 17; ++t) {
    const int v0 = t * 16;
    const int vr = v0 + ln;
    const int vv = (vr < kV) ? vr : (kV - 1);

    bfrag whi, wlo;
    {
      const float* wrow = wbase + (size_t)vv*wstride + q*8;
#pragma unroll
      for (int j = 0; j < 8; ++j) {
        float wv = wrow[j];
        short hi = f2b(wv);
        whi[j] = hi;
        wlo[j] = f2b(wv - b2f(hi));
      }
    }

    float bias = bbase[vv];
    ffrag acc;
#pragma unroll
    for (int i = 0; i < 4; ++i) {
      float a = bias;
      if (ch == 1)      a += TGt[(size_t)trv[i]*kV + vv];
      else if (ch == 2) a += TBRt[(size_t)trv[i]*kV + vv] + TBGt[(size_t)tgv[i]*kV + vv];
      acc[i] = a;
    }

    acc = MFMA16(hvA, wlo, acc);
    acc = MFMA16(hvA, whi, acc);

    if (vr < kV) {
#pragma unroll
      for (int i = 0; i < 4; ++i)
        out[(obase + q*4 + i)*kV + vr] = acc[i];
    }
  }
}

extern "C" void kernel_launch(void* const* d_in, const int* in_sizes, int n_in,
                              void* d_out, int out_size, void* d_ws, size_t ws_size,
                              hipStream_t stream)
{
  const int* x      = (const int*)d_in[0];
  const int* target = (const int*)d_in[1];
  float* wsf = (float*)d_ws;

  norm_kernel<<<16, 256, 0, stream>>>(d_in[2], d_in[3], d_in[4], d_in[5], d_in[6], d_in[7],
                                      d_in[8], d_in[9], d_in[10], d_in[11], d_in[12], d_in[13],
                                      d_in[14], d_in[15], d_in[16], d_in[17], wsf);
  const int prepN = 3*kV*kG + 3*kG*kH + 2*kG*kH + 3*kG + 3*kG + 3*kV*kV;
  prep_kernel<<<(prepN + 255)/256, 256, 0, stream>>>(wsf);
  tfold_kernel<<<(3*kV*kG + 255)/256, 256, 0, stream>>>(wsf);
  recur_all_kernel<<<24, 512, 0, stream>>>(x, wsf);
  logits_kernel<<<3*16*64, 256, 0, stream>>>(target, wsf, (float*)d_out);
}